// Round 2
// baseline (17562.024 us; speedup 1.0000x reference)
//
#include <hip/hip_runtime.h>
#include <hip/hip_bf16.h>
#include <cstdint>
#include <cstddef>

typedef unsigned short u16;
typedef __attribute__((ext_vector_type(8))) short short8;
typedef __attribute__((ext_vector_type(4))) float f32x4;

// ---------------- constants ----------------
#define NB 32          // batch
#define NT 1024        // time steps
#define NH 1024        // hidden
#define TCH 128        // time chunk
#define NCH 8          // number of chunks

// workspace offsets (bytes); total ~177 MB
#define O_XB   0ull                 // x bf16: 64MB
#define O_WIH  67108864ull          // wih bf16 both dirs: 16MB
#define O_WHHP 83886080ull          // whh packed hi/lo frag-linear: 32MB
#define O_BIAS 117440512ull         // bias sums f32: 32KB
#define O_HBUF 117473280ull         // h ping-pong bf16 [dir][buf][b][j]: 256KB
#define O_CST  117735424ull         // c state f32 [dir][b][j]: 256KB
#define O_CNT  117997568ull         // barrier counters: 4KB
#define O_GX   118001664ull         // Gx bf16 chunk [dir][tl][b][npr]: 64MB

__device__ __forceinline__ u16 f2bf(float f){
  union { float f; unsigned u; } v; v.f = f;
  unsigned r = v.u + 0x7FFFu + ((v.u >> 16) & 1u);
  return (u16)(r >> 16);
}
__device__ __forceinline__ float bf2f(u16 h){
  union { unsigned u; float f; } v; v.u = ((unsigned)h) << 16;
  return v.f;
}
__device__ __forceinline__ float sig_f(float x){ return 1.0f / (1.0f + __expf(-x)); }
__device__ __forceinline__ float tanh_f(float x){ return 1.0f - 2.0f / (1.0f + __expf(2.0f * x)); }

__device__ __forceinline__ void g2l16(const void* g, void* l){
  __builtin_amdgcn_global_load_lds(
      (const __attribute__((address_space(1))) unsigned int*)g,
      (__attribute__((address_space(3))) unsigned int*)l, 16, 0, 0);
}

__device__ __forceinline__ float sel4(float s0, float s1, float s2, float s3, int k){
  float a = (k & 1) ? s1 : s0;
  float b = (k & 1) ? s3 : s2;
  return (k & 2) ? b : a;
}

// ---------------- f32 -> bf16 convert ----------------
__global__ void k_cvt(const float* __restrict__ src, u16* __restrict__ dst, int n){
  int i = (blockIdx.x * blockDim.x + threadIdx.x) * 4;
  int stride = gridDim.x * blockDim.x * 4;
  for (; i < n; i += stride){
    float4 v = *(const float4*)(src + i);
    uint2 p;
    p.x = (unsigned)f2bf(v.x) | ((unsigned)f2bf(v.y) << 16);
    p.y = (unsigned)f2bf(v.z) | ((unsigned)f2bf(v.w) << 16);
    *(uint2*)(dst + i) = p;
  }
}

// ---------------- pack Whh into hi/lo fragment-linear layout ----------------
// frag index = (((dir*128 + jg)*2 + ni)*32 + ks)*2 + part ; 1024B per frag (lane*16B)
// lane c=lane&15 -> weight row n = (c>>2)*1024 + jg*8 + ni*4 + (c&3); k-chunk (lane>>4)*8
__global__ void k_pack_whh(const float* __restrict__ whh_f, const float* __restrict__ whh_r,
                           u16* __restrict__ dst){
  int bx = blockIdx.x;              // 512 blocks: dir*256 + jg*2 + ni
  int dir = bx >> 8, rem = bx & 255;
  int jg = rem >> 1, ni = rem & 1;
  const float* whh = dir ? whh_r : whh_f;
  int tid = threadIdx.x;
  int lane = tid & 63, wq = tid >> 6;
  int c = lane & 15;
  int n = (c >> 2) * 1024 + jg * 8 + ni * 4 + (c & 3);
  int kkb = (lane >> 4) * 8;
  size_t fb = ((((size_t)dir * 128 + jg) * 2 + ni) * 32) * 2;
  for (int q = 0; q < 8; q++){
    int ks = wq * 8 + q;
    const float4* p = (const float4*)(whh + (size_t)n * 1024 + ks * 32 + kkb);
    float4 w0 = p[0], w1 = p[1];
    float w[8] = {w0.x, w0.y, w0.z, w0.w, w1.x, w1.y, w1.z, w1.w};
    unsigned hh[4], ll[4];
    #pragma unroll
    for (int e = 0; e < 4; e++){
      u16 h0 = f2bf(w[2*e]),   l0 = f2bf(w[2*e]   - bf2f(f2bf(w[2*e])));
      u16 h1 = f2bf(w[2*e+1]), l1 = f2bf(w[2*e+1] - bf2f(f2bf(w[2*e+1])));
      hh[e] = (unsigned)h0 | ((unsigned)h1 << 16);
      ll[e] = (unsigned)l0 | ((unsigned)l1 << 16);
    }
    uint4* dh = (uint4*)(dst + (fb + (size_t)ks * 2 + 0) * 512 + lane * 8);
    uint4* dl = (uint4*)(dst + (fb + (size_t)ks * 2 + 1) * 512 + lane * 8);
    *dh = make_uint4(hh[0], hh[1], hh[2], hh[3]);
    *dl = make_uint4(ll[0], ll[1], ll[2], ll[3]);
  }
}

// ---------------- init: bias sums, h0->bf16, c state, zero counters ----------------
__global__ void k_init(const float* __restrict__ h0, const float* __restrict__ c0,
                       const float* __restrict__ bih_f, const float* __restrict__ bhh_f,
                       const float* __restrict__ bih_r, const float* __restrict__ bhh_r,
                       u16* __restrict__ hbuf, float* __restrict__ cst,
                       float* __restrict__ bias, int* __restrict__ cnt){
  int i = blockIdx.x * blockDim.x + threadIdx.x;
  int stride = gridDim.x * blockDim.x;
  for (int k = i; k < 32768; k += stride){
    u16 v = f2bf(h0[k]);
    hbuf[k] = v;            // dir0 buf0
    hbuf[65536 + k] = v;    // dir1 buf0
    float cv = c0[k];
    cst[k] = cv;            // dir0
    cst[32768 + k] = cv;    // dir1
  }
  for (int k = i; k < 8192; k += stride){
    if (k < 4096) bias[k] = bih_f[k] + bhh_f[k];
    else          bias[k] = bih_r[k - 4096] + bhh_r[k - 4096];
  }
  for (int k = i; k < 1024; k += stride) cnt[k] = 0;
}

// ---------------- Phase 1: Gx chunk = x @ Wih^T + bias, store bf16 permuted ----------------
// grid (32, 32, 2): n0 = bx*128 (gate cols), by = batch, bz = dir. 128x128 tile, BK=64.
__global__ __launch_bounds__(256, 2) void k_gemm(const u16* __restrict__ xb,
                                                 const u16* __restrict__ wih,
                                                 const float* __restrict__ bias,
                                                 u16* __restrict__ gx, int chunk){
  __shared__ u16 smem[2 * 16384]; // 2 x 32KB frag-linear, frag f at f*512 u16; A:0..15 B:16..31
  const int tid = threadIdx.x;
  const int lane = tid & 63, wid = tid >> 6;
  const int mi = wid >> 1, ni = wid & 1;
  const int c = lane & 15, rg = lane >> 4;
  const int n0 = blockIdx.x * 128;
  const int bb = blockIdx.y;              // batch
  const int dir = blockIdx.z;
  const u16* wd = wih + (size_t)dir * 4194304;

  f32x4 acc[4][4] = {};

  auto stage = [&](int buf, int k0){
    #pragma unroll
    for (int q = 0; q < 8; q++){
      int f = wid * 8 + q;
      int ks = f & 1;
      int kk = k0 + ks * 32 + rg * 8;
      const u16* src;
      if (f < 16){
        int lr = (f >> 1) * 16 + c;       // local t within chunk
        int tg = dir ? (1023 - chunk * TCH - lr) : (chunk * TCH + lr);
        src = xb + (size_t)(bb * 1024 + tg) * 1024 + kk;
      } else {
        int nt = (f - 16) >> 1;
        src = wd + (size_t)(n0 + nt * 16 + c) * 1024 + kk;
      }
      g2l16((const void*)src, (void*)(smem + buf * 16384 + f * 512));
    }
  };

  stage(0, 0);
  asm volatile("s_waitcnt vmcnt(0)" ::: "memory");
  __syncthreads();

  for (int it = 0; it < 16; it++){
    int cur = it & 1;
    if (it < 15) stage(cur ^ 1, (it + 1) * 64);
    const u16* bp = smem + cur * 16384;
    #pragma unroll
    for (int ks = 0; ks < 2; ks++){
      short8 a[4], b[4];
      #pragma unroll
      for (int im = 0; im < 4; im++)
        a[im] = *(const short8*)(bp + ((mi * 4 + im) * 2 + ks) * 512 + lane * 8);
      #pragma unroll
      for (int in_ = 0; in_ < 4; in_++)
        b[in_] = *(const short8*)(bp + 8192 + ((ni * 4 + in_) * 2 + ks) * 512 + lane * 8);
      #pragma unroll
      for (int im = 0; im < 4; im++)
        #pragma unroll
        for (int in_ = 0; in_ < 4; in_++)
          acc[im][in_] = __builtin_amdgcn_mfma_f32_16x16x32_bf16(a[im], b[in_], acc[im][in_], 0, 0, 0);
    }
    asm volatile("s_waitcnt vmcnt(0)" ::: "memory");
    __syncthreads();
  }

  // epilogue: add bias, permute col, store bf16 at gx[dir][tl][b][npr]
  u16* gxd = gx + (size_t)dir * (TCH * 32 * 4096);
  const float* bd = bias + dir * 4096;
  #pragma unroll
  for (int in_ = 0; in_ < 4; in_++){
    int nn = n0 + (ni * 4 + in_) * 16 + c;
    float bv = bd[nn];
    int npr = ((nn & 1023) >> 3) * 32 + ((nn >> 10) << 3) + (nn & 7);
    #pragma unroll
    for (int im = 0; im < 4; im++){
      #pragma unroll
      for (int r = 0; r < 4; r++){
        int tl = (mi * 4 + im) * 16 + rg * 4 + r;   // local t
        gxd[(size_t)(tl * 32 + bb) * 4096 + npr] = f2bf(acc[im][in_][r] + bv);
      }
    }
  }
}

// ---------------- Phase 2: recurrent kernel, one chunk of TCH steps ----------------
// 256 blocks x 256 threads, 1 block/CU. block bx: dir = bx>>7, jg = bx&127 (8 hidden units).
// Whh slice (hi+lo) register-resident. h staged to dual-XOR-swizzled LDS each step.
__global__ __launch_bounds__(256, 1) void k_rnn(const u16* __restrict__ gx,
                                                const u16* __restrict__ whhp,
                                                u16* __restrict__ hbuf,
                                                float* __restrict__ cstate,
                                                float* __restrict__ dout,
                                                int* __restrict__ cnt,
                                                int s0, int bar0){
  __shared__ char smem[65536]; // h tile: row r at r*2048, byte b at b ^ (((r&7)^((b>>8)&7))<<4)
  const int tid = threadIdx.x;
  const int lane = tid & 63, wid = tid >> 6;
  const int mi = wid >> 1, ni = wid & 1;
  const int bx = blockIdx.x;
  const int dir = bx >> 7, jg = bx & 127;
  const int c = lane & 15, rg = lane >> 4;
  const int g = c >> 2, jj = c & 3;
  const int j = jg * 8 + ni * 4 + jj;
  const int row_base = mi * 16 + rg * 4;

  // --- Whh fragments into registers (hi + lo) ---
  short8 Bhi[32], Blo[32];
  {
    size_t fb = ((((size_t)dir * 128 + jg) * 2 + ni) * 32) * 2;
    #pragma unroll
    for (int ks = 0; ks < 32; ks++){
      Bhi[ks] = *(const short8*)(whhp + (fb + ks * 2 + 0) * 512 + lane * 8);
      Blo[ks] = *(const short8*)(whhp + (fb + ks * 2 + 1) * 512 + lane * 8);
    }
  }

  // --- c state (4 batch rows for this lane's hidden j; replicated across gate lanes) ---
  float cst[4];
  #pragma unroll
  for (int r = 0; r < 4; r++) cst[r] = cstate[(size_t)dir * 32768 + (size_t)(row_base + r) * 1024 + j];

  // A-frag read addressing: row = mi*16 + c, byte b = ks*64 + rg*16
  const int arow = mi * 16 + c;
  const int abase = arow * 2048;

  int* root = cnt;
  int* grp = cnt + 32 * (1 + (bx & 15));   // 16 groups x 16 blocks

  for (int t = 0; t < TCH; t++){
    const int s = s0 + t;
    const u16* hcur = hbuf + ((size_t)((dir << 1) + (s & 1))) * 32768;
    u16* hnxt = hbuf + ((size_t)((dir << 1) + ((s + 1) & 1))) * 32768;

    // stage h -> LDS: wave-coalesced global reads, conflict-free swizzled writes
    {
      #pragma unroll
      for (int i = 0; i < 16; i++){
        int row = wid * 8 + (i >> 1);
        uint4 v = *(const uint4*)(hcur + row * 1024 + (i & 1) * 512 + lane * 8);
        int b = (i & 1) * 1024 + lane * 16;
        int swz = (((row & 7) ^ ((b >> 8) & 7)) << 4);
        *(uint4*)(smem + row * 2048 + (b ^ swz)) = v;
      }
    }
    __syncthreads();

    // gates = h @ (Whh_hi + Whh_lo)^T
    f32x4 acc = {0.f, 0.f, 0.f, 0.f};
    #pragma unroll
    for (int ks = 0; ks < 32; ks++){
      int b = ks * 64 + rg * 16;
      int swz = (((arow & 7) ^ ((b >> 8) & 7)) << 4);
      short8 a = *(const short8*)(smem + abase + (b ^ swz));
      acc = __builtin_amdgcn_mfma_f32_16x16x32_bf16(a, Bhi[ks], acc, 0, 0, 0);
      acc = __builtin_amdgcn_mfma_f32_16x16x32_bf16(a, Blo[ks], acc, 0, 0, 0);
    }

    // elementwise LSTM cell (gate exchange via ds_swizzle xor 4/8/12)
    const size_t gof = (size_t)dir * (TCH * 32 * 4096) + (size_t)t * 131072
                     + (size_t)(jg * 32 + g * 8 + ni * 4 + jj);
    #pragma unroll
    for (int r = 0; r < 4; r++){
      float v = acc[r] + bf2f(gx[gof + (size_t)(row_base + r) * 4096]);
      float act = (g == 2) ? tanh_f(v) : sig_f(v);
      float a4  = __int_as_float(__builtin_amdgcn_ds_swizzle(__float_as_int(act), 0x101F));
      float a8  = __int_as_float(__builtin_amdgcn_ds_swizzle(__float_as_int(act), 0x201F));
      float a12 = __int_as_float(__builtin_amdgcn_ds_swizzle(__float_as_int(act), 0x301F));
      float i_s = sel4(act, a4, a8, a12, g);
      float f_s = sel4(act, a4, a8, a12, g ^ 1);
      float g_t = sel4(act, a4, a8, a12, g ^ 2);
      float o_s = sel4(act, a4, a8, a12, g ^ 3);
      float cn = f_s * cst[r] + i_s * g_t;
      cst[r] = cn;
      float hn = o_s * tanh_f(cn);
      if (g == 0){
        hnxt[(size_t)(row_base + r) * 1024 + j] = f2bf(hn);
        if (s == 1023)
          dout[(size_t)dir * 32768 + (size_t)(row_base + r) * 1024 + j] = hn;
        if (t == TCH - 1)
          cstate[(size_t)dir * 32768 + (size_t)(row_base + r) * 1024 + j] = cn;
      }
    }

    // grid barrier (two-level monotonic counters, agent scope); skip after last step
    if (t < TCH - 1){
      __syncthreads();
      if (tid == 0){
        const int bar = bar0 + t;
        int old = __hip_atomic_fetch_add(grp, 1, __ATOMIC_RELEASE, __HIP_MEMORY_SCOPE_AGENT);
        if (old == 16 * (bar + 1) - 1)
          __hip_atomic_fetch_add(root, 1, __ATOMIC_ACQ_REL, __HIP_MEMORY_SCOPE_AGENT);
        const int tgt = 16 * (bar + 1);
        while (__hip_atomic_load(root, __ATOMIC_RELAXED, __HIP_MEMORY_SCOPE_AGENT) < tgt)
          __builtin_amdgcn_s_sleep(2);
        (void)__hip_atomic_load(root, __ATOMIC_ACQUIRE, __HIP_MEMORY_SCOPE_AGENT);
      }
      __syncthreads();
    }
  }
}

// ---------------- host launcher ----------------
extern "C" void kernel_launch(void* const* d_in, const int* in_sizes, int n_in,
                              void* d_out, int out_size, void* d_ws, size_t ws_size,
                              hipStream_t stream){
  const float* x     = (const float*)d_in[0];
  const float* h0    = (const float*)d_in[1];
  const float* c0    = (const float*)d_in[2];
  const float* Wih_f = (const float*)d_in[3];
  const float* Whh_f = (const float*)d_in[4];
  const float* bih_f = (const float*)d_in[5];
  const float* bhh_f = (const float*)d_in[6];
  const float* Wih_r = (const float*)d_in[7];
  const float* Whh_r = (const float*)d_in[8];
  const float* bih_r = (const float*)d_in[9];
  const float* bhh_r = (const float*)d_in[10];
  float* out = (float*)d_out;

  char* ws = (char*)d_ws;
  u16*   xb    = (u16*)(ws + O_XB);
  u16*   wih   = (u16*)(ws + O_WIH);
  u16*   whhp  = (u16*)(ws + O_WHHP);
  float* bias  = (float*)(ws + O_BIAS);
  u16*   hbuf  = (u16*)(ws + O_HBUF);
  float* cstw  = (float*)(ws + O_CST);
  int*   cnt   = (int*)(ws + O_CNT);
  u16*   gx    = (u16*)(ws + O_GX);

  // conversions / packing / init (independent)
  k_cvt<<<2048, 256, 0, stream>>>(x, xb, 32 * 1024 * 1024);
  k_cvt<<<512, 256, 0, stream>>>(Wih_f, wih, 4096 * 1024);
  k_cvt<<<512, 256, 0, stream>>>(Wih_r, wih + 4194304, 4096 * 1024);
  k_pack_whh<<<512, 256, 0, stream>>>(Whh_f, Whh_r, whhp);
  k_init<<<64, 256, 0, stream>>>(h0, c0, bih_f, bhh_f, bih_r, bhh_r, hbuf, cstw, bias, cnt);

  // chunked: input-projection GEMM then TCH recurrent steps, 8x
  for (int ch = 0; ch < NCH; ch++){
    k_gemm<<<dim3(32, 32, 2), 256, 0, stream>>>(xb, wih, bias, gx, ch);
    k_rnn<<<dim3(256), dim3(256), 0, stream>>>(gx, whhp, hbuf, cstw, out, cnt,
                                               ch * TCH, ch * (TCH - 1));
  }
}

// Round 3
// 14278.017 us; speedup vs baseline: 1.2300x; 1.2300x over previous
//
#include <hip/hip_runtime.h>
#include <hip/hip_bf16.h>
#include <cstdint>
#include <cstddef>

typedef unsigned short u16;
typedef unsigned long long u64;
typedef __attribute__((ext_vector_type(8))) short short8;
typedef __attribute__((ext_vector_type(4))) float f32x4;

// ---------------- constants ----------------
#define NB 32          // batch
#define NT 1024        // time steps
#define NH 1024        // hidden
#define TCH 128        // time chunk
#define NCH 8          // number of chunks

// workspace offsets (bytes); total ~177 MB
#define O_XB   0ull                 // x bf16: 64MB
#define O_WIH  67108864ull          // wih bf16 both dirs: 16MB
#define O_WHHP 83886080ull          // whh packed hi/lo frag-linear: 32MB
#define O_BIAS 117440512ull         // bias sums f32: 32KB
#define O_HBUF 117473280ull         // h ping-pong bf16 [dir][buf][b][j]: 256KB
#define O_CST  117735424ull         // c state f32 [dir][b][j]: 256KB
#define O_CNT  117997568ull         // barrier counters: 4KB
#define O_GX   118001664ull         // Gx bf16 chunk [dir][tl][b][npr]: 64MB

__device__ __forceinline__ u16 f2bf(float f){
  union { float f; unsigned u; } v; v.f = f;
  unsigned r = v.u + 0x7FFFu + ((v.u >> 16) & 1u);
  return (u16)(r >> 16);
}
__device__ __forceinline__ float bf2f(u16 h){
  union { unsigned u; float f; } v; v.u = ((unsigned)h) << 16;
  return v.f;
}
__device__ __forceinline__ float sig_f(float x){ return 1.0f / (1.0f + __expf(-x)); }
__device__ __forceinline__ float tanh_f(float x){ return 1.0f - 2.0f / (1.0f + __expf(2.0f * x)); }

__device__ __forceinline__ void g2l16(const void* g, void* l){
  __builtin_amdgcn_global_load_lds(
      (const __attribute__((address_space(1))) unsigned int*)g,
      (__attribute__((address_space(3))) unsigned int*)l, 16, 0, 0);
}

__device__ __forceinline__ float sel4(float s0, float s1, float s2, float s3, int k){
  float a = (k & 1) ? s1 : s0;
  float b = (k & 1) ? s3 : s2;
  return (k & 2) ? b : a;
}

// ---------------- f32 -> bf16 convert ----------------
__global__ void k_cvt(const float* __restrict__ src, u16* __restrict__ dst, int n){
  int i = (blockIdx.x * blockDim.x + threadIdx.x) * 4;
  int stride = gridDim.x * blockDim.x * 4;
  for (; i < n; i += stride){
    float4 v = *(const float4*)(src + i);
    uint2 p;
    p.x = (unsigned)f2bf(v.x) | ((unsigned)f2bf(v.y) << 16);
    p.y = (unsigned)f2bf(v.z) | ((unsigned)f2bf(v.w) << 16);
    *(uint2*)(dst + i) = p;
  }
}

// ---------------- pack Whh into hi/lo fragment-linear layout ----------------
// frag index = (((dir*128 + jg)*2 + ni)*32 + ks)*2 + part ; 1024B per frag (lane*16B)
// lane c=lane&15 -> weight row n = (c>>2)*1024 + jg*8 + ni*4 + (c&3); k-chunk (lane>>4)*8
__global__ void k_pack_whh(const float* __restrict__ whh_f, const float* __restrict__ whh_r,
                           u16* __restrict__ dst){
  int bx = blockIdx.x;              // 512 blocks: dir*256 + jg*2 + ni
  int dir = bx >> 8, rem = bx & 255;
  int jg = rem >> 1, ni = rem & 1;
  const float* whh = dir ? whh_r : whh_f;
  int tid = threadIdx.x;
  int lane = tid & 63, wq = tid >> 6;
  int c = lane & 15;
  int n = (c >> 2) * 1024 + jg * 8 + ni * 4 + (c & 3);
  int kkb = (lane >> 4) * 8;
  size_t fb = ((((size_t)dir * 128 + jg) * 2 + ni) * 32) * 2;
  for (int q = 0; q < 8; q++){
    int ks = wq * 8 + q;
    const float4* p = (const float4*)(whh + (size_t)n * 1024 + ks * 32 + kkb);
    float4 w0 = p[0], w1 = p[1];
    float w[8] = {w0.x, w0.y, w0.z, w0.w, w1.x, w1.y, w1.z, w1.w};
    unsigned hh[4], ll[4];
    #pragma unroll
    for (int e = 0; e < 4; e++){
      u16 h0 = f2bf(w[2*e]),   l0 = f2bf(w[2*e]   - bf2f(f2bf(w[2*e])));
      u16 h1 = f2bf(w[2*e+1]), l1 = f2bf(w[2*e+1] - bf2f(f2bf(w[2*e+1])));
      hh[e] = (unsigned)h0 | ((unsigned)h1 << 16);
      ll[e] = (unsigned)l0 | ((unsigned)l1 << 16);
    }
    uint4* dh = (uint4*)(dst + (fb + (size_t)ks * 2 + 0) * 512 + lane * 8);
    uint4* dl = (uint4*)(dst + (fb + (size_t)ks * 2 + 1) * 512 + lane * 8);
    *dh = make_uint4(hh[0], hh[1], hh[2], hh[3]);
    *dl = make_uint4(ll[0], ll[1], ll[2], ll[3]);
  }
}

// ---------------- init: bias sums, h0->bf16, c state, zero counters ----------------
__global__ void k_init(const float* __restrict__ h0, const float* __restrict__ c0,
                       const float* __restrict__ bih_f, const float* __restrict__ bhh_f,
                       const float* __restrict__ bih_r, const float* __restrict__ bhh_r,
                       u16* __restrict__ hbuf, float* __restrict__ cst,
                       float* __restrict__ bias, int* __restrict__ cnt){
  int i = blockIdx.x * blockDim.x + threadIdx.x;
  int stride = gridDim.x * blockDim.x;
  for (int k = i; k < 32768; k += stride){
    u16 v = f2bf(h0[k]);
    hbuf[k] = v;            // dir0 buf0
    hbuf[65536 + k] = v;    // dir1 buf0
    float cv = c0[k];
    cst[k] = cv;            // dir0
    cst[32768 + k] = cv;    // dir1
  }
  for (int k = i; k < 8192; k += stride){
    if (k < 4096) bias[k] = bih_f[k] + bhh_f[k];
    else          bias[k] = bih_r[k - 4096] + bhh_r[k - 4096];
  }
  for (int k = i; k < 1024; k += stride) cnt[k] = 0;
}

// ---------------- Phase 1: Gx chunk = x @ Wih^T + bias, store bf16 permuted ----------------
// grid (32, 32, 2): n0 = bx*128 (gate cols), by = batch, bz = dir. 128x128 tile, BK=64.
__global__ __launch_bounds__(256, 2) void k_gemm(const u16* __restrict__ xb,
                                                 const u16* __restrict__ wih,
                                                 const float* __restrict__ bias,
                                                 u16* __restrict__ gx, int chunk){
  __shared__ u16 smem[2 * 16384]; // 2 x 32KB frag-linear, frag f at f*512 u16; A:0..15 B:16..31
  const int tid = threadIdx.x;
  const int lane = tid & 63, wid = tid >> 6;
  const int mi = wid >> 1, ni = wid & 1;
  const int c = lane & 15, rg = lane >> 4;
  const int n0 = blockIdx.x * 128;
  const int bb = blockIdx.y;              // batch
  const int dir = blockIdx.z;
  const u16* wd = wih + (size_t)dir * 4194304;

  f32x4 acc[4][4] = {};

  auto stage = [&](int buf, int k0){
    #pragma unroll
    for (int q = 0; q < 8; q++){
      int f = wid * 8 + q;
      int ks = f & 1;
      int kk = k0 + ks * 32 + rg * 8;
      const u16* src;
      if (f < 16){
        int lr = (f >> 1) * 16 + c;       // local t within chunk
        int tg = dir ? (1023 - chunk * TCH - lr) : (chunk * TCH + lr);
        src = xb + (size_t)(bb * 1024 + tg) * 1024 + kk;
      } else {
        int nt = (f - 16) >> 1;
        src = wd + (size_t)(n0 + nt * 16 + c) * 1024 + kk;
      }
      g2l16((const void*)src, (void*)(smem + buf * 16384 + f * 512));
    }
  };

  stage(0, 0);
  asm volatile("s_waitcnt vmcnt(0)" ::: "memory");
  __syncthreads();

  for (int it = 0; it < 16; it++){
    int cur = it & 1;
    if (it < 15) stage(cur ^ 1, (it + 1) * 64);
    const u16* bp = smem + cur * 16384;
    #pragma unroll
    for (int ks = 0; ks < 2; ks++){
      short8 a[4], b[4];
      #pragma unroll
      for (int im = 0; im < 4; im++)
        a[im] = *(const short8*)(bp + ((mi * 4 + im) * 2 + ks) * 512 + lane * 8);
      #pragma unroll
      for (int in_ = 0; in_ < 4; in_++)
        b[in_] = *(const short8*)(bp + 8192 + ((ni * 4 + in_) * 2 + ks) * 512 + lane * 8);
      #pragma unroll
      for (int im = 0; im < 4; im++)
        #pragma unroll
        for (int in_ = 0; in_ < 4; in_++)
          acc[im][in_] = __builtin_amdgcn_mfma_f32_16x16x32_bf16(a[im], b[in_], acc[im][in_], 0, 0, 0);
    }
    asm volatile("s_waitcnt vmcnt(0)" ::: "memory");
    __syncthreads();
  }

  // epilogue: add bias, permute col, store bf16 at gx[dir][tl][b][npr]
  u16* gxd = gx + (size_t)dir * (TCH * 32 * 4096);
  const float* bd = bias + dir * 4096;
  #pragma unroll
  for (int in_ = 0; in_ < 4; in_++){
    int nn = n0 + (ni * 4 + in_) * 16 + c;
    float bv = bd[nn];
    int npr = ((nn & 1023) >> 3) * 32 + ((nn >> 10) << 3) + (nn & 7);
    #pragma unroll
    for (int im = 0; im < 4; im++){
      #pragma unroll
      for (int r = 0; r < 4; r++){
        int tl = (mi * 4 + im) * 16 + rg * 4 + r;   // local t
        gxd[(size_t)(tl * 32 + bb) * 4096 + npr] = f2bf(acc[im][in_][r] + bv);
      }
    }
  }
}

// ---------------- Phase 2: recurrent kernel, one chunk of TCH steps ----------------
// 256 blocks x 256 threads, co-resident. block bx: dir = bx>>7, jg = bx&127 (8 hidden units).
// Whh slice (hi+lo) register-resident. h staged to dual-XOR-swizzled LDS each step.
// Cross-block h exchange: relaxed agent-scope atomics (LLC coherence point) — NO
// acquire/release fences (those emit per-step L2 writeback/invalidate walks = 14us/step).
// Ordering: s_waitcnt vmcnt(0) before arrival-add; counter data-dependency before reads.
__global__ __launch_bounds__(256, 1) void k_rnn(const u16* __restrict__ gx,
                                                const u16* __restrict__ whhp,
                                                u16* __restrict__ hbuf,
                                                float* __restrict__ cstate,
                                                float* __restrict__ dout,
                                                int* __restrict__ cnt,
                                                int s0, int bar0){
  __shared__ char smem[65536]; // h tile: row r at r*2048, byte b at b ^ (((r&7)^((b>>8)&7))<<4)
  __shared__ u16 tb[32][16];   // 4x4 transpose buffer for h_new stores (cols 0..7 used)
  const int tid = threadIdx.x;
  const int lane = tid & 63, wid = tid >> 6;
  const int mi = wid >> 1, ni = wid & 1;
  const int bx = blockIdx.x;
  const int dir = bx >> 7, jg = bx & 127;
  const int c = lane & 15, rg = lane >> 4;
  const int g = c >> 2, jj = c & 3;
  const int j = jg * 8 + ni * 4 + jj;
  const int row_base = mi * 16 + rg * 4;

  // --- Whh fragments into registers (hi + lo) ---
  short8 Bhi[32], Blo[32];
  {
    size_t fb = ((((size_t)dir * 128 + jg) * 2 + ni) * 32) * 2;
    #pragma unroll
    for (int ks = 0; ks < 32; ks++){
      Bhi[ks] = *(const short8*)(whhp + (fb + ks * 2 + 0) * 512 + lane * 8);
      Blo[ks] = *(const short8*)(whhp + (fb + ks * 2 + 1) * 512 + lane * 8);
    }
  }

  // --- c state (4 batch rows for this lane's hidden j; replicated across gate lanes) ---
  float cst[4];
  #pragma unroll
  for (int r = 0; r < 4; r++) cst[r] = cstate[(size_t)dir * 32768 + (size_t)(row_base + r) * 1024 + j];

  // A-frag read addressing: row = mi*16 + c, byte b = ks*64 + rg*16
  const int arow = mi * 16 + c;
  const int abase = arow * 2048;

  int* root = cnt;
  int* grp = cnt + 32 * (1 + (bx & 15));   // 16 groups x 16 blocks

  for (int t = 0; t < TCH; t++){
    const int s = s0 + t;
    const u16* hcur = hbuf + ((size_t)((dir << 1) + (s & 1))) * 32768;
    u16* hnxt = hbuf + ((size_t)((dir << 1) + ((s + 1) & 1))) * 32768;

    // prefetch this step's Gx values (plain loads, overlap with staging + MFMA)
    const size_t gof = (size_t)dir * (TCH * 32 * 4096) + (size_t)t * 131072
                     + (size_t)(jg * 32 + g * 8 + ni * 4 + jj);
    u16 gxu[4];
    #pragma unroll
    for (int r = 0; r < 4; r++)
      gxu[r] = gx[gof + (size_t)(row_base + r) * 4096];

    // stage h -> LDS: relaxed agent-scope 8B atomic loads (LLC), swizzled LDS writes.
    // iteration i covers batch row i: 256 u64 per row, thread tid handles u64 #tid.
    {
      const u64* hc = (const u64*)hcur;
      int bo = tid * 8;
      #pragma unroll
      for (int i = 0; i < 32; i++){
        u64 v = __hip_atomic_load((u64*)(uintptr_t)(hc + i * 256 + tid),
                                  __ATOMIC_RELAXED, __HIP_MEMORY_SCOPE_AGENT);
        int swz = (((i & 7) ^ ((bo >> 8) & 7)) << 4);
        *(u64*)(smem + i * 2048 + (bo ^ swz)) = v;
      }
    }
    __syncthreads();

    // gates = h @ Whh_hi^T (+ h @ Whh_lo^T) — two independent MFMA chains
    f32x4 ah = {0.f, 0.f, 0.f, 0.f};
    f32x4 al = {0.f, 0.f, 0.f, 0.f};
    #pragma unroll
    for (int ks = 0; ks < 32; ks++){
      int b = ks * 64 + rg * 16;
      int swz = (((arow & 7) ^ ((b >> 8) & 7)) << 4);
      short8 a = *(const short8*)(smem + abase + (b ^ swz));
      ah = __builtin_amdgcn_mfma_f32_16x16x32_bf16(a, Bhi[ks], ah, 0, 0, 0);
      al = __builtin_amdgcn_mfma_f32_16x16x32_bf16(a, Blo[ks], al, 0, 0, 0);
    }

    // elementwise LSTM cell (gate exchange via ds_swizzle xor 4/8/12)
    #pragma unroll
    for (int r = 0; r < 4; r++){
      float v = (ah[r] + al[r]) + bf2f(gxu[r]);
      float act = (g == 2) ? tanh_f(v) : sig_f(v);
      float a4  = __int_as_float(__builtin_amdgcn_ds_swizzle(__float_as_int(act), 0x101F));
      float a8  = __int_as_float(__builtin_amdgcn_ds_swizzle(__float_as_int(act), 0x201F));
      float a12 = __int_as_float(__builtin_amdgcn_ds_swizzle(__float_as_int(act), 0x301F));
      float i_s = sel4(act, a4, a8, a12, g);
      float f_s = sel4(act, a4, a8, a12, g ^ 1);
      float g_t = sel4(act, a4, a8, a12, g ^ 2);
      float o_s = sel4(act, a4, a8, a12, g ^ 3);
      float cn = f_s * cst[r] + i_s * g_t;
      cst[r] = cn;
      float hn = o_s * tanh_f(cn);
      if (g == 0){
        tb[row_base + r][ni * 4 + c] = f2bf(hn);
        if (s == 1023)
          dout[(size_t)dir * 32768 + (size_t)(row_base + r) * 1024 + j] = hn;
        if (t == TCH - 1)
          cstate[(size_t)dir * 32768 + (size_t)(row_base + r) * 1024 + j] = cn;
      }
    }
    __syncthreads();   // tb complete

    // h_new stores: wave 0 only, 8B relaxed agent atomics (write-through to LLC)
    if (tid < 64){
      int b = tid >> 1, half = tid & 1;
      u64 v = *(const u64*)&tb[b][half * 4];
      __hip_atomic_store((u64*)(hnxt + (size_t)b * 1024 + jg * 8 + half * 4), v,
                         __ATOMIC_RELAXED, __HIP_MEMORY_SCOPE_AGENT);
    }

    // grid barrier: monotonic counters, all relaxed; explicit vmcnt drain (wave 0
    // issued all h stores, and tid==0 is in wave 0).
    if (t < TCH - 1){
      if (tid == 0){
        asm volatile("s_waitcnt vmcnt(0)" ::: "memory");
        const int bar = bar0 + t;
        int old = __hip_atomic_fetch_add(grp, 1, __ATOMIC_RELAXED, __HIP_MEMORY_SCOPE_AGENT);
        if (old == 16 * (bar + 1) - 1)
          __hip_atomic_fetch_add(root, 1, __ATOMIC_RELAXED, __HIP_MEMORY_SCOPE_AGENT);
        const int tgt = 16 * (bar + 1);
        while (__hip_atomic_load(root, __ATOMIC_RELAXED, __HIP_MEMORY_SCOPE_AGENT) < tgt)
          __builtin_amdgcn_s_sleep(1);
      }
      __syncthreads();
    }
  }
}

// ---------------- host launcher ----------------
extern "C" void kernel_launch(void* const* d_in, const int* in_sizes, int n_in,
                              void* d_out, int out_size, void* d_ws, size_t ws_size,
                              hipStream_t stream){
  const float* x     = (const float*)d_in[0];
  const float* h0    = (const float*)d_in[1];
  const float* c0    = (const float*)d_in[2];
  const float* Wih_f = (const float*)d_in[3];
  const float* Whh_f = (const float*)d_in[4];
  const float* bih_f = (const float*)d_in[5];
  const float* bhh_f = (const float*)d_in[6];
  const float* Wih_r = (const float*)d_in[7];
  const float* Whh_r = (const float*)d_in[8];
  const float* bih_r = (const float*)d_in[9];
  const float* bhh_r = (const float*)d_in[10];
  float* out = (float*)d_out;

  char* ws = (char*)d_ws;
  u16*   xb    = (u16*)(ws + O_XB);
  u16*   wih   = (u16*)(ws + O_WIH);
  u16*   whhp  = (u16*)(ws + O_WHHP);
  float* bias  = (float*)(ws + O_BIAS);
  u16*   hbuf  = (u16*)(ws + O_HBUF);
  float* cstw  = (float*)(ws + O_CST);
  int*   cnt   = (int*)(ws + O_CNT);
  u16*   gx    = (u16*)(ws + O_GX);

  // conversions / packing / init (independent)
  k_cvt<<<2048, 256, 0, stream>>>(x, xb, 32 * 1024 * 1024);
  k_cvt<<<512, 256, 0, stream>>>(Wih_f, wih, 4096 * 1024);
  k_cvt<<<512, 256, 0, stream>>>(Wih_r, wih + 4194304, 4096 * 1024);
  k_pack_whh<<<512, 256, 0, stream>>>(Whh_f, Whh_r, whhp);
  k_init<<<64, 256, 0, stream>>>(h0, c0, bih_f, bhh_f, bih_r, bhh_r, hbuf, cstw, bias, cnt);

  // chunked: input-projection GEMM then TCH recurrent steps, 8x
  for (int ch = 0; ch < NCH; ch++){
    k_gemm<<<dim3(32, 32, 2), 256, 0, stream>>>(xb, wih, bias, gx, ch);
    k_rnn<<<dim3(256), dim3(256), 0, stream>>>(gx, whhp, hbuf, cstw, out, cnt,
                                               ch * TCH, ch * (TCH - 1));
  }
}